// Round 1
// baseline (393.998 us; speedup 1.0000x reference)
//
#include <hip/hip_runtime.h>

// MHA forward: B=2, S=2048, D=1024, H=16, hd=64. fp32 in/out, bf16 MFMA inside.
// ws layout (bf16/ushort elems): q[32*2048*64] | k[same] | vt[32*64*2048] | ctx[4096*1024]
// total 16M elems = 32 MB.

typedef __attribute__((ext_vector_type(8))) __bf16 bf16x8;
typedef __attribute__((ext_vector_type(4))) float f32x4;

__device__ __forceinline__ unsigned short f2bf(float f) {
    union { float f; unsigned u; } v; v.f = f;
    unsigned r = v.u + 0x7fffu + ((v.u >> 16) & 1u);  // RNE
    return (unsigned short)(r >> 16);
}

// ---------------- GEMM1: qkv = X @ Wqkv (+bqkv), scatter to q/k/vt ----------------
__global__ __launch_bounds__(256) void gemm_qkv(
    const float* __restrict__ X, const float* __restrict__ W, const float* __restrict__ bias,
    unsigned short* __restrict__ qws, unsigned short* __restrict__ kws,
    unsigned short* __restrict__ vtws)
{
    const int K = 1024, N = 3072;
    __shared__ __align__(16) unsigned short As[128][72];
    __shared__ __align__(16) unsigned short Bs[128][72];
    const int tid = threadIdx.x;
    const int m0 = blockIdx.y * 128, n0 = blockIdx.x * 128;
    const int wave = tid >> 6, lane = tid & 63;
    const int wm = (wave >> 1) * 64, wn = (wave & 1) * 64;
    const int quad = lane >> 4, l16 = lane & 15;

    f32x4 acc[4][4];
    const f32x4 Z4 = {0.f, 0.f, 0.f, 0.f};
#pragma unroll
    for (int i = 0; i < 4; i++)
#pragma unroll
        for (int j = 0; j < 4; j++) acc[i][j] = Z4;

    for (int k0 = 0; k0 < K; k0 += 64) {
        __syncthreads();
        // stage A: 128 rows x 64 cols fp32 -> bf16
#pragma unroll
        for (int i = 0; i < 8; i++) {
            int idx = tid + i * 256;
            int row = idx >> 4, c4 = (idx & 15) * 4;
            float4 v = *(const float4*)(X + (size_t)(m0 + row) * K + k0 + c4);
            ushort4 o; o.x = f2bf(v.x); o.y = f2bf(v.y); o.z = f2bf(v.z); o.w = f2bf(v.w);
            *(ushort4*)&As[row][c4] = o;
        }
        // stage B transposed: W[k0+kr][n0+c] -> Bs[c][kr]
#pragma unroll
        for (int i = 0; i < 8; i++) {
            int idx = tid + i * 256;
            int kr = idx >> 5, c4 = (idx & 31) * 4;
            float4 v = *(const float4*)(W + (size_t)(k0 + kr) * N + n0 + c4);
            Bs[c4 + 0][kr] = f2bf(v.x);
            Bs[c4 + 1][kr] = f2bf(v.y);
            Bs[c4 + 2][kr] = f2bf(v.z);
            Bs[c4 + 3][kr] = f2bf(v.w);
        }
        __syncthreads();
#pragma unroll
        for (int kk = 0; kk < 2; kk++) {
            int kb = kk * 32 + quad * 8;
            bf16x8 af[4], bfr[4];
#pragma unroll
            for (int mi = 0; mi < 4; mi++) af[mi] = *(const bf16x8*)&As[wm + mi * 16 + l16][kb];
#pragma unroll
            for (int ni = 0; ni < 4; ni++) bfr[ni] = *(const bf16x8*)&Bs[wn + ni * 16 + l16][kb];
#pragma unroll
            for (int mi = 0; mi < 4; mi++)
#pragma unroll
                for (int ni = 0; ni < 4; ni++)
                    acc[mi][ni] = __builtin_amdgcn_mfma_f32_16x16x32_bf16(af[mi], bfr[ni], acc[mi][ni], 0, 0, 0);
        }
    }
    // epilogue: col -> (h, t, d); row -> (b, s)
#pragma unroll
    for (int mi = 0; mi < 4; mi++)
#pragma unroll
        for (int ni = 0; ni < 4; ni++) {
            int col = n0 + wn + ni * 16 + l16;
            int h = col / 192, rem = col % 192, t = rem >> 6, d = rem & 63;
            float bv = bias[col];
#pragma unroll
            for (int r = 0; r < 4; r++) {
                int row = m0 + wm + mi * 16 + quad * 4 + r;
                int b = row >> 11, s = row & 2047;
                unsigned short val = f2bf(acc[mi][ni][r] + bv);
                size_t bh = (size_t)(b * 16 + h);
                if (t == 0)      qws[(bh * 2048 + s) * 64 + d] = val;
                else if (t == 1) kws[(bh * 2048 + s) * 64 + d] = val;
                else             vtws[(bh * 64 + d) * 2048 + s] = val;
            }
        }
}

// ---------------- Flash attention (causal), one block = 128 q-rows x 1 head ----------------
__global__ __launch_bounds__(256) void attn(
    const unsigned short* __restrict__ qws, const unsigned short* __restrict__ kws,
    const unsigned short* __restrict__ vtws, unsigned short* __restrict__ ctx)
{
    __shared__ __align__(16) unsigned short Qs[128][72];
    __shared__ __align__(16) unsigned short Ks[64][72];
    __shared__ __align__(16) unsigned short Vt[64][72];
    __shared__ __align__(16) unsigned short Ps[4][32][72];

    const int tid = threadIdx.x;
    const int wave = tid >> 6, lane = tid & 63, quad = lane >> 4, l16 = lane & 15;
    const int bh = blockIdx.y;
    const int q0 = blockIdx.x * 128;
    const unsigned short* Q  = qws + (size_t)bh * 2048 * 64;
    const unsigned short* Kp = kws + (size_t)bh * 2048 * 64;
    const unsigned short* Vp = vtws + (size_t)bh * 64 * 2048;

    // load Q tile 128x64 (1024 x 16B)
#pragma unroll
    for (int i = 0; i < 4; i++) {
        int idx = tid + i * 256;
        int row = idx >> 3, c = (idx & 7) * 8;
        *(uint4*)&Qs[row][c] = *(const uint4*)(Q + (size_t)(q0 + row) * 64 + c);
    }

    const int wq = wave * 32;
    f32x4 o[2][4];
    const f32x4 Z4 = {0.f, 0.f, 0.f, 0.f};
#pragma unroll
    for (int i = 0; i < 2; i++)
#pragma unroll
        for (int j = 0; j < 4; j++) o[i][j] = Z4;
    float mrow[2][4], lrow[2][4];
#pragma unroll
    for (int i = 0; i < 2; i++)
#pragma unroll
        for (int r = 0; r < 4; r++) { mrow[i][r] = -3.0e38f; lrow[i][r] = 0.f; }

    const int jmax = q0 / 64 + 2;
    for (int j = 0; j < jmax; j++) {
        int kb0 = j * 64;
        __syncthreads();
#pragma unroll
        for (int i = 0; i < 2; i++) {
            int idx = tid + i * 256;
            int row = idx >> 3, c = (idx & 7) * 8;
            *(uint4*)&Ks[row][c] = *(const uint4*)(Kp + (size_t)(kb0 + row) * 64 + c);
            *(uint4*)&Vt[row][c] = *(const uint4*)(Vp + (size_t)row * 2048 + kb0 + c);
        }
        __syncthreads();
        // S = Q K^T  (per wave: 32 q x 64 keys)
        f32x4 sc[2][4];
#pragma unroll
        for (int mi = 0; mi < 2; mi++)
#pragma unroll
            for (int ni = 0; ni < 4; ni++) sc[mi][ni] = Z4;
#pragma unroll
        for (int kk = 0; kk < 2; kk++) {
            int kd = kk * 32 + quad * 8;
            bf16x8 aq[2], bk[4];
#pragma unroll
            for (int mi = 0; mi < 2; mi++) aq[mi] = *(const bf16x8*)&Qs[wq + mi * 16 + l16][kd];
#pragma unroll
            for (int ni = 0; ni < 4; ni++) bk[ni] = *(const bf16x8*)&Ks[ni * 16 + l16][kd];
#pragma unroll
            for (int mi = 0; mi < 2; mi++)
#pragma unroll
                for (int ni = 0; ni < 4; ni++)
                    sc[mi][ni] = __builtin_amdgcn_mfma_f32_16x16x32_bf16(aq[mi], bk[ni], sc[mi][ni], 0, 0, 0);
        }
        // online softmax per q-row (row = quad*4+r, data spread over 16 lanes)
#pragma unroll
        for (int mi = 0; mi < 2; mi++) {
#pragma unroll
            for (int r = 0; r < 4; r++) {
                int qg = q0 + wq + mi * 16 + quad * 4 + r;
                float mx = -3.0e38f;
#pragma unroll
                for (int ni = 0; ni < 4; ni++) {
                    int kg = kb0 + ni * 16 + l16;
                    float v = sc[mi][ni][r] * 0.125f;  // 1/sqrt(64)
                    if (kg > qg) v = -3.0e38f;         // causal mask
                    sc[mi][ni][r] = v;
                    mx = fmaxf(mx, v);
                }
#pragma unroll
                for (int off = 1; off < 16; off <<= 1) mx = fmaxf(mx, __shfl_xor(mx, off));
                float mnew = fmaxf(mrow[mi][r], mx);
                float alpha = __expf(mrow[mi][r] - mnew);
                mrow[mi][r] = mnew;
                float rs = 0.f;
#pragma unroll
                for (int ni = 0; ni < 4; ni++) {
                    float p = __expf(sc[mi][ni][r] - mnew);
                    sc[mi][ni][r] = p;
                    rs += p;
                }
#pragma unroll
                for (int off = 1; off < 16; off <<= 1) rs += __shfl_xor(rs, off);
                lrow[mi][r] = lrow[mi][r] * alpha + rs;
#pragma unroll
                for (int di = 0; di < 4; di++) o[mi][di][r] *= alpha;
                int qloc = mi * 16 + quad * 4 + r;
#pragma unroll
                for (int ni = 0; ni < 4; ni++)
                    Ps[wave][qloc][ni * 16 + l16] = f2bf(sc[mi][ni][r]);
            }
        }
        __syncthreads();  // P C-layout -> A-layout via LDS round-trip
        // O += P V   (K-dim = 64 keys)
#pragma unroll
        for (int kk = 0; kk < 2; kk++) {
            int kp = kk * 32 + quad * 8;
            bf16x8 ap[2], bv[4];
#pragma unroll
            for (int mi = 0; mi < 2; mi++) ap[mi] = *(const bf16x8*)&Ps[wave][mi * 16 + l16][kp];
#pragma unroll
            for (int di = 0; di < 4; di++) bv[di] = *(const bf16x8*)&Vt[di * 16 + l16][kp];
#pragma unroll
            for (int mi = 0; mi < 2; mi++)
#pragma unroll
                for (int di = 0; di < 4; di++)
                    o[mi][di] = __builtin_amdgcn_mfma_f32_16x16x32_bf16(ap[mi], bv[di], o[mi][di], 0, 0, 0);
        }
    }
    // epilogue: ctx[b, s, h*64+d] bf16
    const int b = bh >> 4, h = bh & 15;
#pragma unroll
    for (int mi = 0; mi < 2; mi++)
#pragma unroll
        for (int r = 0; r < 4; r++) {
            int qg = q0 + wq + mi * 16 + quad * 4 + r;
            float inv = 1.0f / lrow[mi][r];
#pragma unroll
            for (int di = 0; di < 4; di++) {
                int d = di * 16 + l16;
                ctx[(size_t)(b * 2048 + qg) * 1024 + h * 64 + d] = f2bf(o[mi][di][r] * inv);
            }
        }
}

// ---------------- GEMM2: out = ctx @ Wo + bo (fp32 out) ----------------
__global__ __launch_bounds__(256) void gemm_out(
    const unsigned short* __restrict__ Ctx, const float* __restrict__ W,
    const float* __restrict__ bias, float* __restrict__ Out)
{
    const int K = 1024, N = 1024;
    __shared__ __align__(16) unsigned short As[128][72];
    __shared__ __align__(16) unsigned short Bs[128][72];
    const int tid = threadIdx.x;
    const int m0 = blockIdx.y * 128, n0 = blockIdx.x * 128;
    const int wave = tid >> 6, lane = tid & 63;
    const int wm = (wave >> 1) * 64, wn = (wave & 1) * 64;
    const int quad = lane >> 4, l16 = lane & 15;

    f32x4 acc[4][4];
    const f32x4 Z4 = {0.f, 0.f, 0.f, 0.f};
#pragma unroll
    for (int i = 0; i < 4; i++)
#pragma unroll
        for (int j = 0; j < 4; j++) acc[i][j] = Z4;

    for (int k0 = 0; k0 < K; k0 += 64) {
        __syncthreads();
        // stage A (already bf16): 128x64 = 1024 x 16B
#pragma unroll
        for (int i = 0; i < 4; i++) {
            int idx = tid + i * 256;
            int row = idx >> 3, c = (idx & 7) * 8;
            *(uint4*)&As[row][c] = *(const uint4*)(Ctx + (size_t)(m0 + row) * K + k0 + c);
        }
        // stage B transposed fp32->bf16
#pragma unroll
        for (int i = 0; i < 8; i++) {
            int idx = tid + i * 256;
            int kr = idx >> 5, c4 = (idx & 31) * 4;
            float4 v = *(const float4*)(W + (size_t)(k0 + kr) * N + n0 + c4);
            Bs[c4 + 0][kr] = f2bf(v.x);
            Bs[c4 + 1][kr] = f2bf(v.y);
            Bs[c4 + 2][kr] = f2bf(v.z);
            Bs[c4 + 3][kr] = f2bf(v.w);
        }
        __syncthreads();
#pragma unroll
        for (int kk = 0; kk < 2; kk++) {
            int kb = kk * 32 + quad * 8;
            bf16x8 af[4], bfr[4];
#pragma unroll
            for (int mi = 0; mi < 4; mi++) af[mi] = *(const bf16x8*)&As[wm + mi * 16 + l16][kb];
#pragma unroll
            for (int ni = 0; ni < 4; ni++) bfr[ni] = *(const bf16x8*)&Bs[wn + ni * 16 + l16][kb];
#pragma unroll
            for (int mi = 0; mi < 4; mi++)
#pragma unroll
                for (int ni = 0; ni < 4; ni++)
                    acc[mi][ni] = __builtin_amdgcn_mfma_f32_16x16x32_bf16(af[mi], bfr[ni], acc[mi][ni], 0, 0, 0);
        }
    }
#pragma unroll
    for (int mi = 0; mi < 4; mi++)
#pragma unroll
        for (int ni = 0; ni < 4; ni++) {
            int col = n0 + wn + ni * 16 + l16;
            float bv = bias[col];
#pragma unroll
            for (int r = 0; r < 4; r++) {
                int row = m0 + wm + mi * 16 + quad * 4 + r;
                Out[(size_t)row * N + col] = acc[mi][ni][r] + bv;
            }
        }
}

extern "C" void kernel_launch(void* const* d_in, const int* in_sizes, int n_in,
                              void* d_out, int out_size, void* d_ws, size_t ws_size,
                              hipStream_t stream) {
    const float* x    = (const float*)d_in[0];
    const float* Wqkv = (const float*)d_in[1];
    const float* bqkv = (const float*)d_in[2];
    const float* Wo   = (const float*)d_in[3];
    const float* bo   = (const float*)d_in[4];
    float* out = (float*)d_out;

    unsigned short* q   = (unsigned short*)d_ws;
    unsigned short* k   = q + (size_t)4194304;   // 32*2048*64
    unsigned short* vt  = k + (size_t)4194304;
    unsigned short* ctx = vt + (size_t)4194304;

    gemm_qkv<<<dim3(24, 32), 256, 0, stream>>>(x, Wqkv, bqkv, q, k, vt);
    attn<<<dim3(16, 32), 256, 0, stream>>>(q, k, vt, ctx);
    gemm_out<<<dim3(8, 32), 256, 0, stream>>>(ctx, Wo, bo, out);
}

// Round 2
// 310.415 us; speedup vs baseline: 1.2693x; 1.2693x over previous
//
#include <hip/hip_runtime.h>

// MHA forward: B=2, S=2048, D=1024, H=16, hd=64. fp32 in/out, bf16 MFMA inside.
// ws regions (ushort elems, 4194304 each): q | k | vt | ctx
//   WqkvT (3072x1024 bf16) aliases ctx region (dead until attn writes it).
//   WoT   (1024x1024 bf16) aliases q region (dead after attn).

typedef __attribute__((ext_vector_type(8))) __bf16 bf16x8;
typedef __attribute__((ext_vector_type(4))) float f32x4;

__device__ __forceinline__ unsigned short f2bf(float f) {
    union { float f; unsigned u; } v; v.f = f;
    unsigned r = v.u + 0x7fffu + ((v.u >> 16) & 1u);  // RNE
    return (unsigned short)(r >> 16);
}

__device__ __forceinline__ void async_copy16(const unsigned short* g, unsigned short* l) {
    __builtin_amdgcn_global_load_lds(
        (const __attribute__((address_space(1))) unsigned int*)g,
        (__attribute__((address_space(3))) unsigned int*)l, 16, 0, 0);
}

// ---------------- transpose + convert: in fp32 [K][N] -> out bf16 [N][K] ----------------
__global__ __launch_bounds__(256) void transpose_f32_bf16(
    const float* __restrict__ in, unsigned short* __restrict__ out, int K, int N)
{
    __shared__ float T[64][65];
    const int tid = threadIdx.x;
    const int n0 = blockIdx.x * 64, k0 = blockIdx.y * 64;
#pragma unroll
    for (int i = 0; i < 4; i++) {
        int idx = tid + i * 256;
        int r = idx >> 4, c4 = (idx & 15) * 4;
        float4 v = *(const float4*)(in + (size_t)(k0 + r) * N + n0 + c4);
        T[r][c4 + 0] = v.x; T[r][c4 + 1] = v.y; T[r][c4 + 2] = v.z; T[r][c4 + 3] = v.w;
    }
    __syncthreads();
#pragma unroll
    for (int i = 0; i < 4; i++) {
        int idx = tid + i * 256;
        int n = idx >> 4, k4 = (idx & 15) * 4;
        ushort4 o;
        o.x = f2bf(T[k4 + 0][n]); o.y = f2bf(T[k4 + 1][n]);
        o.z = f2bf(T[k4 + 2][n]); o.w = f2bf(T[k4 + 3][n]);
        *(ushort4*)(out + (size_t)(n0 + n) * K + k0 + k4) = o;
    }
}

// ---------------- GEMM1: qkv = X @ Wqkv (+bqkv), scatter to q/k(prescaled)/vt ----------------
// LDS layout (both A and B): row n = 64 ushorts (128B); 16B group g stored at g ^ (n&7).
__global__ __launch_bounds__(256) void gemm_qkv(
    const float* __restrict__ X, const unsigned short* __restrict__ WT,  // [3072][1024] bf16
    const float* __restrict__ bias,
    unsigned short* __restrict__ qws, unsigned short* __restrict__ kws,
    unsigned short* __restrict__ vtws)
{
    const int K = 1024, N = 3072;
    __shared__ __align__(16) unsigned short As[128 * 64];
    __shared__ __align__(16) unsigned short Bs[128 * 64];
    const int tid = threadIdx.x;
    const int m0 = blockIdx.y * 128, n0 = blockIdx.x * 128;
    const int wave = tid >> 6, lane = tid & 63;
    const int wm = (wave >> 1) * 64, wn = (wave & 1) * 64;
    const int quad = lane >> 4, l16 = lane & 15;
    const int lrow = lane >> 3, lgrp = lane & 7;   // staging: 8 lanes per row
    const int sg = lgrp ^ lrow;                    // swizzled source group for linear LDS slot

    f32x4 acc[4][4];
    const f32x4 Z4 = {0.f, 0.f, 0.f, 0.f};
#pragma unroll
    for (int i = 0; i < 4; i++)
#pragma unroll
        for (int j = 0; j < 4; j++) acc[i][j] = Z4;

    for (int k0 = 0; k0 < K; k0 += 64) {
        __syncthreads();
        // B stage: async global->LDS, 4 wave-calls x 8 rows. Lane L -> row nb+L/8, slot L%8.
#pragma unroll
        for (int c = 0; c < 4; c++) {
            int nb = (wave * 4 + c) * 8;
            const unsigned short* src = WT + (size_t)(n0 + nb + lrow) * K + k0 + sg * 8;
            async_copy16(src, &Bs[nb * 64]);
        }
        // A stage: fp32->bf16 VALU convert, swizzled 16B writes (conflict-free).
#pragma unroll
        for (int i = 0; i < 4; i++) {
            int idx = tid + i * 256;
            int m = idx >> 3, g = idx & 7;
            const float* xp = X + (size_t)(m0 + m) * K + k0 + g * 8;
            float4 v0 = *(const float4*)xp;
            float4 v1 = *(const float4*)(xp + 4);
            ushort4 a, b;
            a.x = f2bf(v0.x); a.y = f2bf(v0.y); a.z = f2bf(v0.z); a.w = f2bf(v0.w);
            b.x = f2bf(v1.x); b.y = f2bf(v1.y); b.z = f2bf(v1.z); b.w = f2bf(v1.w);
            int pg = g ^ (m & 7);
            *(ushort4*)&As[m * 64 + pg * 8] = a;
            *(ushort4*)&As[m * 64 + pg * 8 + 4] = b;
        }
        __syncthreads();
#pragma unroll
        for (int kk = 0; kk < 2; kk++) {
            int G = kk * 4 + quad;
            int pg = (G ^ (l16 & 7)) * 8;
            bf16x8 af[4], bfr[4];
#pragma unroll
            for (int mi = 0; mi < 4; mi++) af[mi] = *(const bf16x8*)&As[(wm + mi * 16 + l16) * 64 + pg];
#pragma unroll
            for (int ni = 0; ni < 4; ni++) bfr[ni] = *(const bf16x8*)&Bs[(wn + ni * 16 + l16) * 64 + pg];
#pragma unroll
            for (int mi = 0; mi < 4; mi++)
#pragma unroll
                for (int ni = 0; ni < 4; ni++)
                    acc[mi][ni] = __builtin_amdgcn_mfma_f32_16x16x32_bf16(af[mi], bfr[ni], acc[mi][ni], 0, 0, 0);
        }
    }
    // epilogue: col -> (h, t, d); row -> (b, s). K gets 1/sqrt(hd)=0.125 folded in (exact in bf16).
#pragma unroll
    for (int mi = 0; mi < 4; mi++)
#pragma unroll
        for (int ni = 0; ni < 4; ni++) {
            int col = n0 + wn + ni * 16 + l16;
            int h = col / 192, rem = col % 192, t = rem >> 6, d = rem & 63;
            float bv = bias[col];
#pragma unroll
            for (int r = 0; r < 4; r++) {
                int row = m0 + wm + mi * 16 + quad * 4 + r;
                int b = row >> 11, s = row & 2047;
                float val = acc[mi][ni][r] + bv;
                size_t bh = (size_t)(b * 16 + h);
                if (t == 0)      qws[(bh * 2048 + s) * 64 + d] = f2bf(val);
                else if (t == 1) kws[(bh * 2048 + s) * 64 + d] = f2bf(val * 0.125f);
                else             vtws[(bh * 64 + d) * 2048 + s] = f2bf(val);
            }
        }
}

// ---------------- Flash attention (causal), one block = 128 q-rows x 1 head ----------------
__global__ __launch_bounds__(256) void attn(
    const unsigned short* __restrict__ qws, const unsigned short* __restrict__ kws,
    const unsigned short* __restrict__ vtws, unsigned short* __restrict__ ctx)
{
    __shared__ __align__(16) unsigned short Qs[128][72];
    __shared__ __align__(16) unsigned short Ks[64][72];
    __shared__ __align__(16) unsigned short Vt[64][72];
    __shared__ __align__(16) unsigned short Ps[4][32][72];

    const int tid = threadIdx.x;
    const int wave = tid >> 6, lane = tid & 63, quad = lane >> 4, l16 = lane & 15;
    const int bh = blockIdx.y;
    const int q0 = blockIdx.x * 128;
    const unsigned short* Q  = qws + (size_t)bh * 2048 * 64;
    const unsigned short* Kp = kws + (size_t)bh * 2048 * 64;
    const unsigned short* Vp = vtws + (size_t)bh * 64 * 2048;

#pragma unroll
    for (int i = 0; i < 4; i++) {
        int idx = tid + i * 256;
        int row = idx >> 3, c = (idx & 7) * 8;
        *(uint4*)&Qs[row][c] = *(const uint4*)(Q + (size_t)(q0 + row) * 64 + c);
    }

    const int wq = wave * 32;
    f32x4 o[2][4];
    const f32x4 Z4 = {0.f, 0.f, 0.f, 0.f};
#pragma unroll
    for (int i = 0; i < 2; i++)
#pragma unroll
        for (int j = 0; j < 4; j++) o[i][j] = Z4;
    float mrow[2][4], lrow[2][4];
#pragma unroll
    for (int i = 0; i < 2; i++)
#pragma unroll
        for (int r = 0; r < 4; r++) { mrow[i][r] = -3.0e38f; lrow[i][r] = 0.f; }

    const int jmax = q0 / 64 + 2;
    for (int j = 0; j < jmax; j++) {
        int kb0 = j * 64;
        __syncthreads();
#pragma unroll
        for (int i = 0; i < 2; i++) {
            int idx = tid + i * 256;
            int row = idx >> 3, c = (idx & 7) * 8;
            *(uint4*)&Ks[row][c] = *(const uint4*)(Kp + (size_t)(kb0 + row) * 64 + c);
            *(uint4*)&Vt[row][c] = *(const uint4*)(Vp + (size_t)row * 2048 + kb0 + c);
        }
        __syncthreads();
        // S = Q K^T (K prescaled by 1/sqrt(hd))
        f32x4 sc[2][4];
#pragma unroll
        for (int mi = 0; mi < 2; mi++)
#pragma unroll
            for (int ni = 0; ni < 4; ni++) sc[mi][ni] = Z4;
#pragma unroll
        for (int kk = 0; kk < 2; kk++) {
            int kd = kk * 32 + quad * 8;
            bf16x8 aq[2], bk[4];
#pragma unroll
            for (int mi = 0; mi < 2; mi++) aq[mi] = *(const bf16x8*)&Qs[wq + mi * 16 + l16][kd];
#pragma unroll
            for (int ni = 0; ni < 4; ni++) bk[ni] = *(const bf16x8*)&Ks[ni * 16 + l16][kd];
#pragma unroll
            for (int mi = 0; mi < 2; mi++)
#pragma unroll
                for (int ni = 0; ni < 4; ni++)
                    sc[mi][ni] = __builtin_amdgcn_mfma_f32_16x16x32_bf16(aq[mi], bk[ni], sc[mi][ni], 0, 0, 0);
        }
        // online softmax per q-row
#pragma unroll
        for (int mi = 0; mi < 2; mi++) {
            bool need_mask = (kb0 + 63 > q0 + wq + mi * 16);
#pragma unroll
            for (int r = 0; r < 4; r++) {
                int qg = q0 + wq + mi * 16 + quad * 4 + r;
                float mx = -3.0e38f;
                if (need_mask) {
#pragma unroll
                    for (int ni = 0; ni < 4; ni++) {
                        int kg = kb0 + ni * 16 + l16;
                        float v = sc[mi][ni][r];
                        if (kg > qg) v = -3.0e38f;
                        sc[mi][ni][r] = v;
                        mx = fmaxf(mx, v);
                    }
                } else {
#pragma unroll
                    for (int ni = 0; ni < 4; ni++) mx = fmaxf(mx, sc[mi][ni][r]);
                }
#pragma unroll
                for (int off = 1; off < 16; off <<= 1) mx = fmaxf(mx, __shfl_xor(mx, off));
                float mnew = fmaxf(mrow[mi][r], mx);
                float alpha = __expf(mrow[mi][r] - mnew);
                mrow[mi][r] = mnew;
                float rs = 0.f;
#pragma unroll
                for (int ni = 0; ni < 4; ni++) {
                    float p = __expf(sc[mi][ni][r] - mnew);
                    sc[mi][ni][r] = p;
                    rs += p;
                }
#pragma unroll
                for (int off = 1; off < 16; off <<= 1) rs += __shfl_xor(rs, off);
                lrow[mi][r] = lrow[mi][r] * alpha + rs;
#pragma unroll
                for (int di = 0; di < 4; di++) o[mi][di][r] *= alpha;
                int qloc = mi * 16 + quad * 4 + r;
#pragma unroll
                for (int ni = 0; ni < 4; ni++)
                    Ps[wave][qloc][ni * 16 + l16] = f2bf(sc[mi][ni][r]);
            }
        }
        __syncthreads();  // P C-layout -> A-layout via LDS round-trip
        // O += P V
#pragma unroll
        for (int kk = 0; kk < 2; kk++) {
            int kp = kk * 32 + quad * 8;
            bf16x8 ap[2], bv[4];
#pragma unroll
            for (int mi = 0; mi < 2; mi++) ap[mi] = *(const bf16x8*)&Ps[wave][mi * 16 + l16][kp];
#pragma unroll
            for (int di = 0; di < 4; di++) bv[di] = *(const bf16x8*)&Vt[di * 16 + l16][kp];
#pragma unroll
            for (int mi = 0; mi < 2; mi++)
#pragma unroll
                for (int di = 0; di < 4; di++)
                    o[mi][di] = __builtin_amdgcn_mfma_f32_16x16x32_bf16(ap[mi], bv[di], o[mi][di], 0, 0, 0);
        }
    }
    const int b = bh >> 4, h = bh & 15;
#pragma unroll
    for (int mi = 0; mi < 2; mi++)
#pragma unroll
        for (int r = 0; r < 4; r++) {
            int qg = q0 + wq + mi * 16 + quad * 4 + r;
            float inv = 1.0f / lrow[mi][r];
#pragma unroll
            for (int di = 0; di < 4; di++) {
                int d = di * 16 + l16;
                ctx[(size_t)(b * 2048 + qg) * 1024 + h * 64 + d] = f2bf(o[mi][di][r] * inv);
            }
        }
}

// ---------------- GEMM2: out = ctx @ Wo + bo (fp32 out) ----------------
__global__ __launch_bounds__(256) void gemm_out(
    const unsigned short* __restrict__ Ctx, const unsigned short* __restrict__ WT,  // [1024][1024] bf16
    const float* __restrict__ bias, float* __restrict__ Out)
{
    const int K = 1024, N = 1024;
    __shared__ __align__(16) unsigned short As[128 * 64];
    __shared__ __align__(16) unsigned short Bs[128 * 64];
    const int tid = threadIdx.x;
    const int m0 = blockIdx.y * 128, n0 = blockIdx.x * 128;
    const int wave = tid >> 6, lane = tid & 63;
    const int wm = (wave >> 1) * 64, wn = (wave & 1) * 64;
    const int quad = lane >> 4, l16 = lane & 15;
    const int lrow = lane >> 3, lgrp = lane & 7;
    const int sg = lgrp ^ lrow;

    f32x4 acc[4][4];
    const f32x4 Z4 = {0.f, 0.f, 0.f, 0.f};
#pragma unroll
    for (int i = 0; i < 4; i++)
#pragma unroll
        for (int j = 0; j < 4; j++) acc[i][j] = Z4;

    for (int k0 = 0; k0 < K; k0 += 64) {
        __syncthreads();
#pragma unroll
        for (int c = 0; c < 4; c++) {
            int nb = (wave * 4 + c) * 8;
            async_copy16(Ctx + (size_t)(m0 + nb + lrow) * K + k0 + sg * 8, &As[nb * 64]);
            async_copy16(WT  + (size_t)(n0 + nb + lrow) * K + k0 + sg * 8, &Bs[nb * 64]);
        }
        __syncthreads();
#pragma unroll
        for (int kk = 0; kk < 2; kk++) {
            int G = kk * 4 + quad;
            int pg = (G ^ (l16 & 7)) * 8;
            bf16x8 af[4], bfr[4];
#pragma unroll
            for (int mi = 0; mi < 4; mi++) af[mi] = *(const bf16x8*)&As[(wm + mi * 16 + l16) * 64 + pg];
#pragma unroll
            for (int ni = 0; ni < 4; ni++) bfr[ni] = *(const bf16x8*)&Bs[(wn + ni * 16 + l16) * 64 + pg];
#pragma unroll
            for (int mi = 0; mi < 4; mi++)
#pragma unroll
                for (int ni = 0; ni < 4; ni++)
                    acc[mi][ni] = __builtin_amdgcn_mfma_f32_16x16x32_bf16(af[mi], bfr[ni], acc[mi][ni], 0, 0, 0);
        }
    }
#pragma unroll
    for (int mi = 0; mi < 4; mi++)
#pragma unroll
        for (int ni = 0; ni < 4; ni++) {
            int col = n0 + wn + ni * 16 + l16;
            float bv = bias[col];
#pragma unroll
            for (int r = 0; r < 4; r++) {
                int row = m0 + wm + mi * 16 + quad * 4 + r;
                Out[(size_t)row * N + col] = acc[mi][ni][r] + bv;
            }
        }
}

extern "C" void kernel_launch(void* const* d_in, const int* in_sizes, int n_in,
                              void* d_out, int out_size, void* d_ws, size_t ws_size,
                              hipStream_t stream) {
    const float* x    = (const float*)d_in[0];
    const float* Wqkv = (const float*)d_in[1];
    const float* bqkv = (const float*)d_in[2];
    const float* Wo   = (const float*)d_in[3];
    const float* bo   = (const float*)d_in[4];
    float* out = (float*)d_out;

    unsigned short* q   = (unsigned short*)d_ws;
    unsigned short* k   = q + (size_t)4194304;   // 32*2048*64
    unsigned short* vt  = k + (size_t)4194304;
    unsigned short* ctx = vt + (size_t)4194304;
    unsigned short* wqkvT = ctx;                 // alias: dead until attn runs
    unsigned short* woT   = q;                   // alias: q dead after attn

    transpose_f32_bf16<<<dim3(48, 16), 256, 0, stream>>>(Wqkv, wqkvT, 1024, 3072);
    gemm_qkv<<<dim3(24, 32), 256, 0, stream>>>(x, wqkvT, bqkv, q, k, vt);
    attn<<<dim3(16, 32), 256, 0, stream>>>(q, k, vt, ctx);
    transpose_f32_bf16<<<dim3(16, 16), 256, 0, stream>>>(Wo, woT, 1024, 1024);
    gemm_out<<<dim3(8, 32), 256, 0, stream>>>(ctx, woT, bo, out);
}

// Round 4
// 234.681 us; speedup vs baseline: 1.6789x; 1.3227x over previous
//
#include <hip/hip_runtime.h>

// MHA forward: B=2, S=2048, D=1024, H=16, hd=64. fp32 in/out, bf16 MFMA inside.
// ws regions (ushort elems, 4194304 each): q | k | vt | ctx
//   WqkvT (3072x1024 bf16) aliases ctx region (dead until attn writes it).
//   WoT   (1024x1024 bf16) aliases q region (dead after attn).
// K is prescaled by 0.125*log2(e) so attention softmax runs in exp2 domain.

typedef __attribute__((ext_vector_type(8))) __bf16 bf16x8;
typedef __attribute__((ext_vector_type(4))) float f32x4;
typedef __attribute__((ext_vector_type(4))) short short4v;

__device__ __forceinline__ unsigned short f2bf(float f) {
    union { float f; unsigned u; } v; v.f = f;
    unsigned r = v.u + 0x7fffu + ((v.u >> 16) & 1u);  // RNE
    return (unsigned short)(r >> 16);
}

__device__ __forceinline__ void async_copy16(const unsigned short* g, unsigned short* l) {
    __builtin_amdgcn_global_load_lds(
        (const __attribute__((address_space(1))) unsigned int*)g,
        (__attribute__((address_space(3))) unsigned int*)l, 16, 0, 0);
}

// v_mfma_f32_16x16x16_bf16 (gfx950 ISA §10). Host pass must only typecheck —
// the builtin is device-only, so gate on __HIP_DEVICE_COMPILE__.
__device__ __forceinline__ f32x4 mfma16x16x16(short4v a, short4v b, f32x4 c) {
#if defined(__HIP_DEVICE_COMPILE__)
    return __builtin_amdgcn_mfma_f32_16x16x16bf16_1k(a, b, c, 0, 0, 0);
#else
    return c;
#endif
}

// ---------------- transpose + convert: in fp32 [K][N] -> out bf16 [N][K] ----------------
__global__ __launch_bounds__(256) void transpose_f32_bf16(
    const float* __restrict__ in, unsigned short* __restrict__ out, int K, int N)
{
    __shared__ float T[64][65];
    const int tid = threadIdx.x;
    const int n0 = blockIdx.x * 64, k0 = blockIdx.y * 64;
#pragma unroll
    for (int i = 0; i < 4; i++) {
        int idx = tid + i * 256;
        int r = idx >> 4, c4 = (idx & 15) * 4;
        float4 v = *(const float4*)(in + (size_t)(k0 + r) * N + n0 + c4);
        T[r][c4 + 0] = v.x; T[r][c4 + 1] = v.y; T[r][c4 + 2] = v.z; T[r][c4 + 3] = v.w;
    }
    __syncthreads();
#pragma unroll
    for (int i = 0; i < 4; i++) {
        int idx = tid + i * 256;
        int n = idx >> 4, k4 = (idx & 15) * 4;
        ushort4 o;
        o.x = f2bf(T[k4 + 0][n]); o.y = f2bf(T[k4 + 1][n]);
        o.z = f2bf(T[k4 + 2][n]); o.w = f2bf(T[k4 + 3][n]);
        *(ushort4*)(out + (size_t)(n0 + n) * K + k0 + k4) = o;
    }
}

// ---------------- GEMM1: qkv = X @ Wqkv (+bqkv), scatter to q/k(prescaled)/vt ----------------
__global__ __launch_bounds__(256) void gemm_qkv(
    const float* __restrict__ X, const unsigned short* __restrict__ WT,  // [3072][1024] bf16
    const float* __restrict__ bias,
    unsigned short* __restrict__ qws, unsigned short* __restrict__ kws,
    unsigned short* __restrict__ vtws)
{
    const int K = 1024, N = 3072;
    __shared__ __align__(16) unsigned short As[128 * 64];
    __shared__ __align__(16) unsigned short Bs[128 * 64];
    const int tid = threadIdx.x;
    const int m0 = blockIdx.y * 128, n0 = blockIdx.x * 128;
    const int wave = tid >> 6, lane = tid & 63;
    const int wm = (wave >> 1) * 64, wn = (wave & 1) * 64;
    const int quad = lane >> 4, l16 = lane & 15;
    const int lrow = lane >> 3, lgrp = lane & 7;
    const int sg = lgrp ^ lrow;

    f32x4 acc[4][4];
    const f32x4 Z4 = {0.f, 0.f, 0.f, 0.f};
#pragma unroll
    for (int i = 0; i < 4; i++)
#pragma unroll
        for (int j = 0; j < 4; j++) acc[i][j] = Z4;

    for (int k0 = 0; k0 < K; k0 += 64) {
        __syncthreads();
#pragma unroll
        for (int c = 0; c < 4; c++) {
            int nb = (wave * 4 + c) * 8;
            async_copy16(WT + (size_t)(n0 + nb + lrow) * K + k0 + sg * 8, &Bs[nb * 64]);
        }
#pragma unroll
        for (int i = 0; i < 4; i++) {
            int idx = tid + i * 256;
            int m = idx >> 3, g = idx & 7;
            const float* xp = X + (size_t)(m0 + m) * K + k0 + g * 8;
            float4 v0 = *(const float4*)xp;
            float4 v1 = *(const float4*)(xp + 4);
            ushort4 a, b;
            a.x = f2bf(v0.x); a.y = f2bf(v0.y); a.z = f2bf(v0.z); a.w = f2bf(v0.w);
            b.x = f2bf(v1.x); b.y = f2bf(v1.y); b.z = f2bf(v1.z); b.w = f2bf(v1.w);
            int pg = g ^ (m & 7);
            *(ushort4*)&As[m * 64 + pg * 8] = a;
            *(ushort4*)&As[m * 64 + pg * 8 + 4] = b;
        }
        __syncthreads();
#pragma unroll
        for (int kk = 0; kk < 2; kk++) {
            int G = kk * 4 + quad;
            int pg = (G ^ (l16 & 7)) * 8;
            bf16x8 af[4], bfr[4];
#pragma unroll
            for (int mi = 0; mi < 4; mi++) af[mi] = *(const bf16x8*)&As[(wm + mi * 16 + l16) * 64 + pg];
#pragma unroll
            for (int ni = 0; ni < 4; ni++) bfr[ni] = *(const bf16x8*)&Bs[(wn + ni * 16 + l16) * 64 + pg];
#pragma unroll
            for (int mi = 0; mi < 4; mi++)
#pragma unroll
                for (int ni = 0; ni < 4; ni++)
                    acc[mi][ni] = __builtin_amdgcn_mfma_f32_16x16x32_bf16(af[mi], bfr[ni], acc[mi][ni], 0, 0, 0);
        }
    }
    // epilogue: col -> (h, t, d); row -> (b, s). K gets 0.125*log2e folded in (exp2 softmax).
#pragma unroll
    for (int mi = 0; mi < 4; mi++)
#pragma unroll
        for (int ni = 0; ni < 4; ni++) {
            int col = n0 + wn + ni * 16 + l16;
            int h = col / 192, rem = col % 192, t = rem >> 6, d = rem & 63;
            float bv = bias[col];
#pragma unroll
            for (int r = 0; r < 4; r++) {
                int row = m0 + wm + mi * 16 + quad * 4 + r;
                int b = row >> 11, s = row & 2047;
                float val = acc[mi][ni][r] + bv;
                size_t bh = (size_t)(b * 16 + h);
                if (t == 0)      qws[(bh * 2048 + s) * 64 + d] = f2bf(val);
                else if (t == 1) kws[(bh * 2048 + s) * 64 + d] = f2bf(val * 0.18033688f);
                else             vtws[(bh * 64 + d) * 2048 + s] = f2bf(val);
            }
        }
}

// ---------------- Flash attention (causal), S-transposed formulation ----------------
// Block = 128 q-rows x 1 head. S^T = K Q^T so each lane owns a fixed q (=lane&15):
// softmax is pure per-lane VALU (exp2, no max pass, deferred row-sum), and S^T's
// C-regs are exactly the B-fragment of 16x16x16 MFMA for O^T += V^T P^T.
__global__ __launch_bounds__(256) void attn(
    const unsigned short* __restrict__ qws, const unsigned short* __restrict__ kws,
    const unsigned short* __restrict__ vtws, unsigned short* __restrict__ ctx)
{
    __shared__ __align__(16) unsigned short Qs[128 * 64];  // swizzled rows
    __shared__ __align__(16) unsigned short Ks[64 * 64];   // swizzled rows
    __shared__ __align__(16) unsigned short Vt[64][72];    // padded [d][key]

    const int tid = threadIdx.x;
    const int wave = tid >> 6, lane = tid & 63, quad = lane >> 4, l16 = lane & 15;
    const int lrow = lane >> 3, lgrp = lane & 7;
    const int sg = lgrp ^ lrow;

    // work mapping: long tiles first; blocks i and i+256 pair tiles t and 15-t
    const int i = blockIdx.x;
    const int idx = i & 255;
    const int tile = (i < 256) ? (15 - (idx >> 5)) : (idx >> 5);
    const int bh = idx & 31;
    const int q0 = tile * 128;

    const unsigned short* Q  = qws + (size_t)bh * 2048 * 64;
    const unsigned short* Kp = kws + (size_t)bh * 2048 * 64;
    const unsigned short* Vp = vtws + (size_t)bh * 64 * 2048;

    // stage Q once (async, swizzled)
#pragma unroll
    for (int c = 0; c < 4; c++) {
        int rb = (wave * 4 + c) * 8;
        async_copy16(Q + (size_t)(q0 + rb + lrow) * 64 + sg * 8, &Qs[rb * 64]);
    }

    const int wq = wave * 32;
    f32x4 o[4][2];  // [d-tile][q-tile], O^T C-layout: d=quad*4+r, q=l16
    const f32x4 Z4 = {0.f, 0.f, 0.f, 0.f};
#pragma unroll
    for (int dt = 0; dt < 4; dt++)
#pragma unroll
        for (int qt = 0; qt < 2; qt++) o[dt][qt] = Z4;
    float lsum[2] = {0.f, 0.f};

    const int jmax = tile * 2 + 2;
    for (int j = 0; j < jmax; j++) {
        const int kb0 = j * 64;
        __syncthreads();
#pragma unroll
        for (int c = 0; c < 2; c++) {
            int rb = (wave * 2 + c) * 8;
            async_copy16(Kp + (size_t)(kb0 + rb + lrow) * 64 + sg * 8, &Ks[rb * 64]);
        }
#pragma unroll
        for (int ii = 0; ii < 2; ii++) {
            int id2 = tid + ii * 256;
            int row = id2 >> 3, c = (id2 & 7) * 8;
            *(uint4*)&Vt[row][c] = *(const uint4*)(Vp + (size_t)row * 2048 + kb0 + c);
        }
        __syncthreads();

        if (kb0 <= q0 + wq + 31) {  // wave-uniform: skip fully-masked quadrants
            // S^T = K Q^T : per wave 64 keys x 32 q
            f32x4 sc[4][2];
#pragma unroll
            for (int kt = 0; kt < 4; kt++)
#pragma unroll
                for (int qt = 0; qt < 2; qt++) sc[kt][qt] = Z4;
#pragma unroll
            for (int kk = 0; kk < 2; kk++) {
                int pg = ((kk * 4 + quad) ^ (l16 & 7)) * 8;
                bf16x8 ak[4], bq[2];
#pragma unroll
                for (int kt = 0; kt < 4; kt++) ak[kt] = *(const bf16x8*)&Ks[(kt * 16 + l16) * 64 + pg];
#pragma unroll
                for (int qt = 0; qt < 2; qt++) bq[qt] = *(const bf16x8*)&Qs[(wq + qt * 16 + l16) * 64 + pg];
#pragma unroll
                for (int kt = 0; kt < 4; kt++)
#pragma unroll
                    for (int qt = 0; qt < 2; qt++)
                        sc[kt][qt] = __builtin_amdgcn_mfma_f32_16x16x32_bf16(ak[kt], bq[qt], sc[kt][qt], 0, 0, 0);
            }
            // p = exp2(s); masked -> 0; per-lane partial row-sum (no cross-lane ops)
            short4v pb[4][2];
#pragma unroll
            for (int qt = 0; qt < 2; qt++) {
                int qg = q0 + wq + qt * 16 + l16;
#pragma unroll
                for (int kt = 0; kt < 4; kt++) {
#pragma unroll
                    for (int r = 0; r < 4; r++) {
                        int key = kb0 + kt * 16 + quad * 4 + r;
                        float p = exp2f(sc[kt][qt][r]);
                        p = (key <= qg) ? p : 0.f;
                        lsum[qt] += p;
                        pb[kt][qt][r] = (short)f2bf(p);
                    }
                }
            }
            // O^T += V^T P^T  (16x16x16: A = V^T from LDS, B = P^T straight from regs)
#pragma unroll
            for (int kt = 0; kt < 4; kt++) {
#pragma unroll
                for (int dt = 0; dt < 4; dt++) {
                    short4v av = *(const short4v*)&Vt[dt * 16 + l16][kt * 16 + quad * 4];
#pragma unroll
                    for (int qt = 0; qt < 2; qt++)
                        o[dt][qt] = mfma16x16x16(av, pb[kt][qt], o[dt][qt]);
                }
            }
        }
    }
    // reduce row-sums over the 4 quads (only cross-lane ops in the kernel)
#pragma unroll
    for (int qt = 0; qt < 2; qt++) {
        lsum[qt] += __shfl_xor(lsum[qt], 16);
        lsum[qt] += __shfl_xor(lsum[qt], 32);
    }
    // epilogue: ctx[b, s, h*64+d] bf16, 8B stores (d contiguous in r)
    const int b = bh >> 4, h = bh & 15;
#pragma unroll
    for (int qt = 0; qt < 2; qt++) {
        int qg = q0 + wq + qt * 16 + l16;
        float inv = 1.0f / lsum[qt];
#pragma unroll
        for (int dt = 0; dt < 4; dt++) {
            ushort4 ov;
            ov.x = f2bf(o[dt][qt][0] * inv);
            ov.y = f2bf(o[dt][qt][1] * inv);
            ov.z = f2bf(o[dt][qt][2] * inv);
            ov.w = f2bf(o[dt][qt][3] * inv);
            *(ushort4*)(ctx + (size_t)(b * 2048 + qg) * 1024 + h * 64 + dt * 16 + quad * 4) = ov;
        }
    }
}

// ---------------- GEMM2: out = ctx @ Wo + bo (fp32 out) ----------------
__global__ __launch_bounds__(256) void gemm_out(
    const unsigned short* __restrict__ Ctx, const unsigned short* __restrict__ WT,  // [1024][1024] bf16
    const float* __restrict__ bias, float* __restrict__ Out)
{
    const int K = 1024, N = 1024;
    __shared__ __align__(16) unsigned short As[128 * 64];
    __shared__ __align__(16) unsigned short Bs[128 * 64];
    const int tid = threadIdx.x;
    const int m0 = blockIdx.y * 128, n0 = blockIdx.x * 128;
    const int wave = tid >> 6, lane = tid & 63;
    const int wm = (wave >> 1) * 64, wn = (wave & 1) * 64;
    const int quad = lane >> 4, l16 = lane & 15;
    const int lrow = lane >> 3, lgrp = lane & 7;
    const int sg = lgrp ^ lrow;

    f32x4 acc[4][4];
    const f32x4 Z4 = {0.f, 0.f, 0.f, 0.f};
#pragma unroll
    for (int i = 0; i < 4; i++)
#pragma unroll
        for (int j = 0; j < 4; j++) acc[i][j] = Z4;

    for (int k0 = 0; k0 < K; k0 += 64) {
        __syncthreads();
#pragma unroll
        for (int c = 0; c < 4; c++) {
            int nb = (wave * 4 + c) * 8;
            async_copy16(Ctx + (size_t)(m0 + nb + lrow) * K + k0 + sg * 8, &As[nb * 64]);
            async_copy16(WT  + (size_t)(n0 + nb + lrow) * K + k0 + sg * 8, &Bs[nb * 64]);
        }
        __syncthreads();
#pragma unroll
        for (int kk = 0; kk < 2; kk++) {
            int G = kk * 4 + quad;
            int pg = (G ^ (l16 & 7)) * 8;
            bf16x8 af[4], bfr[4];
#pragma unroll
            for (int mi = 0; mi < 4; mi++) af[mi] = *(const bf16x8*)&As[(wm + mi * 16 + l16) * 64 + pg];
#pragma unroll
            for (int ni = 0; ni < 4; ni++) bfr[ni] = *(const bf16x8*)&Bs[(wn + ni * 16 + l16) * 64 + pg];
#pragma unroll
            for (int mi = 0; mi < 4; mi++)
#pragma unroll
                for (int ni = 0; ni < 4; ni++)
                    acc[mi][ni] = __builtin_amdgcn_mfma_f32_16x16x32_bf16(af[mi], bfr[ni], acc[mi][ni], 0, 0, 0);
        }
    }
#pragma unroll
    for (int mi = 0; mi < 4; mi++)
#pragma unroll
        for (int ni = 0; ni < 4; ni++) {
            int col = n0 + wn + ni * 16 + l16;
            float bv = bias[col];
#pragma unroll
            for (int r = 0; r < 4; r++) {
                int row = m0 + wm + mi * 16 + quad * 4 + r;
                Out[(size_t)row * N + col] = acc[mi][ni][r] + bv;
            }
        }
}

extern "C" void kernel_launch(void* const* d_in, const int* in_sizes, int n_in,
                              void* d_out, int out_size, void* d_ws, size_t ws_size,
                              hipStream_t stream) {
    const float* x    = (const float*)d_in[0];
    const float* Wqkv = (const float*)d_in[1];
    const float* bqkv = (const float*)d_in[2];
    const float* Wo   = (const float*)d_in[3];
    const float* bo   = (const float*)d_in[4];
    float* out = (float*)d_out;

    unsigned short* q   = (unsigned short*)d_ws;
    unsigned short* k   = q + (size_t)4194304;   // 32*2048*64
    unsigned short* vt  = k + (size_t)4194304;
    unsigned short* ctx = vt + (size_t)4194304;
    unsigned short* wqkvT = ctx;                 // alias: dead until attn runs
    unsigned short* woT   = q;                   // alias: q dead after attn

    transpose_f32_bf16<<<dim3(48, 16), 256, 0, stream>>>(Wqkv, wqkvT, 1024, 3072);
    gemm_qkv<<<dim3(24, 32), 256, 0, stream>>>(x, wqkvT, bqkv, q, k, vt);
    attn<<<dim3(512), 256, 0, stream>>>(q, k, vt, ctx);
    transpose_f32_bf16<<<dim3(16, 16), 256, 0, stream>>>(Wo, woT, 1024, 1024);
    gemm_out<<<dim3(8, 32), 256, 0, stream>>>(ctx, woT, bo, out);
}

// Round 5
// 223.892 us; speedup vs baseline: 1.7598x; 1.0482x over previous
//
#include <hip/hip_runtime.h>

// MHA forward: B=2, S=2048, D=1024, H=16, hd=64. fp32 in/out, bf16 MFMA inside.
// ws regions (ushort elems, 4194304 each): q | k | vt | ctx | xbf(optional 5th)
//   WqkvT (3072x1024 bf16) aliases ctx region (dead until attn writes it).
//   WoT   (1024x1024 bf16) aliases q region (dead after attn).
// K is prescaled by 0.125*log2(e) so attention softmax runs in exp2 domain.

typedef __attribute__((ext_vector_type(8))) __bf16 bf16x8;
typedef __attribute__((ext_vector_type(4))) float f32x4;
typedef __attribute__((ext_vector_type(4))) short short4v;

__device__ __forceinline__ unsigned short f2bf(float f) {
    union { float f; unsigned u; } v; v.f = f;
    unsigned r = v.u + 0x7fffu + ((v.u >> 16) & 1u);  // RNE
    return (unsigned short)(r >> 16);
}

__device__ __forceinline__ void async_copy16(const unsigned short* g, unsigned short* l) {
    __builtin_amdgcn_global_load_lds(
        (const __attribute__((address_space(1))) unsigned int*)g,
        (__attribute__((address_space(3))) unsigned int*)l, 16, 0, 0);
}

// v_mfma_f32_16x16x16_bf16; builtin is device-only, host pass only typechecks.
__device__ __forceinline__ f32x4 mfma16x16x16(short4v a, short4v b, f32x4 c) {
#if defined(__HIP_DEVICE_COMPILE__)
    return __builtin_amdgcn_mfma_f32_16x16x16bf16_1k(a, b, c, 0, 0, 0);
#else
    return c;
#endif
}

// ---------------- elementwise convert: fp32 -> bf16, n multiple of 2048 ----------------
__global__ __launch_bounds__(256) void convert_f32_bf16(
    const float* __restrict__ in, unsigned short* __restrict__ out)
{
    size_t i = ((size_t)blockIdx.x * 256 + threadIdx.x) * 8;
    float4 v0 = *(const float4*)(in + i);
    float4 v1 = *(const float4*)(in + i + 4);
    ushort4 a, b;
    a.x = f2bf(v0.x); a.y = f2bf(v0.y); a.z = f2bf(v0.z); a.w = f2bf(v0.w);
    b.x = f2bf(v1.x); b.y = f2bf(v1.y); b.z = f2bf(v1.z); b.w = f2bf(v1.w);
    *(ushort4*)(out + i) = a;
    *(ushort4*)(out + i + 4) = b;
}

// ---------------- transpose + convert: in fp32 [K][N] -> out bf16 [N][K] ----------------
__global__ __launch_bounds__(256) void transpose_f32_bf16(
    const float* __restrict__ in, unsigned short* __restrict__ out, int K, int N)
{
    __shared__ float T[64][65];
    const int tid = threadIdx.x;
    const int n0 = blockIdx.x * 64, k0 = blockIdx.y * 64;
#pragma unroll
    for (int i = 0; i < 4; i++) {
        int idx = tid + i * 256;
        int r = idx >> 4, c4 = (idx & 15) * 4;
        float4 v = *(const float4*)(in + (size_t)(k0 + r) * N + n0 + c4);
        T[r][c4 + 0] = v.x; T[r][c4 + 1] = v.y; T[r][c4 + 2] = v.z; T[r][c4 + 3] = v.w;
    }
    __syncthreads();
#pragma unroll
    for (int i = 0; i < 4; i++) {
        int idx = tid + i * 256;
        int n = idx >> 4, k4 = (idx & 15) * 4;
        ushort4 o;
        o.x = f2bf(T[k4 + 0][n]); o.y = f2bf(T[k4 + 1][n]);
        o.z = f2bf(T[k4 + 2][n]); o.w = f2bf(T[k4 + 3][n]);
        *(ushort4*)(out + (size_t)(n0 + n) * K + k0 + k4) = o;
    }
}

// -------- shared epilogue for the qkv GEMM: scatter to q / k(prescaled) / vt --------
__device__ __forceinline__ void qkv_epilogue(
    f32x4 (&acc)[4][4], const float* __restrict__ bias,
    unsigned short* __restrict__ qws, unsigned short* __restrict__ kws,
    unsigned short* __restrict__ vtws,
    int m0, int n0, int wm, int wn, int quad, int l16)
{
#pragma unroll
    for (int mi = 0; mi < 4; mi++)
#pragma unroll
        for (int ni = 0; ni < 4; ni++) {
            int col = n0 + wn + ni * 16 + l16;
            int h = col / 192, rem = col % 192, t = rem >> 6, d = rem & 63;
            float bv = bias[col];
#pragma unroll
            for (int r = 0; r < 4; r++) {
                int row = m0 + wm + mi * 16 + quad * 4 + r;
                int b = row >> 11, s = row & 2047;
                float val = acc[mi][ni][r] + bv;
                size_t bh = (size_t)(b * 16 + h);
                if (t == 0)      qws[(bh * 2048 + s) * 64 + d] = f2bf(val);
                else if (t == 1) kws[(bh * 2048 + s) * 64 + d] = f2bf(val * 0.18033688f);
                else             vtws[(bh * 64 + d) * 2048 + s] = f2bf(val);
            }
        }
}

// ---------------- GEMM1 (preferred): A already bf16, all-async staging ----------------
__global__ __launch_bounds__(256) void gemm_qkv_bf(
    const unsigned short* __restrict__ Xbf,  // [4096][1024] bf16
    const unsigned short* __restrict__ WT,   // [3072][1024] bf16
    const float* __restrict__ bias,
    unsigned short* __restrict__ qws, unsigned short* __restrict__ kws,
    unsigned short* __restrict__ vtws)
{
    const int K = 1024;
    __shared__ __align__(16) unsigned short As[128 * 64];
    __shared__ __align__(16) unsigned short Bs[128 * 64];
    const int tid = threadIdx.x;
    const int m0 = blockIdx.y * 128, n0 = blockIdx.x * 128;
    const int wave = tid >> 6, lane = tid & 63;
    const int wm = (wave >> 1) * 64, wn = (wave & 1) * 64;
    const int quad = lane >> 4, l16 = lane & 15;
    const int lrow = lane >> 3, lgrp = lane & 7;
    const int sg = lgrp ^ lrow;

    f32x4 acc[4][4];
    const f32x4 Z4 = {0.f, 0.f, 0.f, 0.f};
#pragma unroll
    for (int i = 0; i < 4; i++)
#pragma unroll
        for (int j = 0; j < 4; j++) acc[i][j] = Z4;

    for (int k0 = 0; k0 < K; k0 += 64) {
        __syncthreads();
#pragma unroll
        for (int c = 0; c < 4; c++) {
            int nb = (wave * 4 + c) * 8;
            async_copy16(Xbf + (size_t)(m0 + nb + lrow) * K + k0 + sg * 8, &As[nb * 64]);
            async_copy16(WT  + (size_t)(n0 + nb + lrow) * K + k0 + sg * 8, &Bs[nb * 64]);
        }
        __syncthreads();
#pragma unroll
        for (int kk = 0; kk < 2; kk++) {
            int pg = ((kk * 4 + quad) ^ (l16 & 7)) * 8;
            bf16x8 af[4], bfr[4];
#pragma unroll
            for (int mi = 0; mi < 4; mi++) af[mi] = *(const bf16x8*)&As[(wm + mi * 16 + l16) * 64 + pg];
#pragma unroll
            for (int ni = 0; ni < 4; ni++) bfr[ni] = *(const bf16x8*)&Bs[(wn + ni * 16 + l16) * 64 + pg];
#pragma unroll
            for (int mi = 0; mi < 4; mi++)
#pragma unroll
                for (int ni = 0; ni < 4; ni++)
                    acc[mi][ni] = __builtin_amdgcn_mfma_f32_16x16x32_bf16(af[mi], bfr[ni], acc[mi][ni], 0, 0, 0);
        }
    }
    qkv_epilogue(acc, bias, qws, kws, vtws, m0, n0, wm, wn, quad, l16);
}

// ---------------- GEMM1 (fallback, ws too small): fp32 A staged via VALU ----------------
__global__ __launch_bounds__(256) void gemm_qkv(
    const float* __restrict__ X, const unsigned short* __restrict__ WT,
    const float* __restrict__ bias,
    unsigned short* __restrict__ qws, unsigned short* __restrict__ kws,
    unsigned short* __restrict__ vtws)
{
    const int K = 1024;
    __shared__ __align__(16) unsigned short As[128 * 64];
    __shared__ __align__(16) unsigned short Bs[128 * 64];
    const int tid = threadIdx.x;
    const int m0 = blockIdx.y * 128, n0 = blockIdx.x * 128;
    const int wave = tid >> 6, lane = tid & 63;
    const int wm = (wave >> 1) * 64, wn = (wave & 1) * 64;
    const int quad = lane >> 4, l16 = lane & 15;
    const int lrow = lane >> 3, lgrp = lane & 7;
    const int sg = lgrp ^ lrow;

    f32x4 acc[4][4];
    const f32x4 Z4 = {0.f, 0.f, 0.f, 0.f};
#pragma unroll
    for (int i = 0; i < 4; i++)
#pragma unroll
        for (int j = 0; j < 4; j++) acc[i][j] = Z4;

    for (int k0 = 0; k0 < K; k0 += 64) {
        __syncthreads();
#pragma unroll
        for (int c = 0; c < 4; c++) {
            int nb = (wave * 4 + c) * 8;
            async_copy16(WT + (size_t)(n0 + nb + lrow) * K + k0 + sg * 8, &Bs[nb * 64]);
        }
#pragma unroll
        for (int i = 0; i < 4; i++) {
            int idx = tid + i * 256;
            int m = idx >> 3, g = idx & 7;
            const float* xp = X + (size_t)(m0 + m) * K + k0 + g * 8;
            float4 v0 = *(const float4*)xp;
            float4 v1 = *(const float4*)(xp + 4);
            ushort4 a, b;
            a.x = f2bf(v0.x); a.y = f2bf(v0.y); a.z = f2bf(v0.z); a.w = f2bf(v0.w);
            b.x = f2bf(v1.x); b.y = f2bf(v1.y); b.z = f2bf(v1.z); b.w = f2bf(v1.w);
            int pg = g ^ (m & 7);
            *(ushort4*)&As[m * 64 + pg * 8] = a;
            *(ushort4*)&As[m * 64 + pg * 8 + 4] = b;
        }
        __syncthreads();
#pragma unroll
        for (int kk = 0; kk < 2; kk++) {
            int pg = ((kk * 4 + quad) ^ (l16 & 7)) * 8;
            bf16x8 af[4], bfr[4];
#pragma unroll
            for (int mi = 0; mi < 4; mi++) af[mi] = *(const bf16x8*)&As[(wm + mi * 16 + l16) * 64 + pg];
#pragma unroll
            for (int ni = 0; ni < 4; ni++) bfr[ni] = *(const bf16x8*)&Bs[(wn + ni * 16 + l16) * 64 + pg];
#pragma unroll
            for (int mi = 0; mi < 4; mi++)
#pragma unroll
                for (int ni = 0; ni < 4; ni++)
                    acc[mi][ni] = __builtin_amdgcn_mfma_f32_16x16x32_bf16(af[mi], bfr[ni], acc[mi][ni], 0, 0, 0);
        }
    }
    qkv_epilogue(acc, bias, qws, kws, vtws, m0, n0, wm, wn, quad, l16);
}

// ---------------- Flash attention (causal), S-transposed formulation ----------------
__global__ __launch_bounds__(256) void attn(
    const unsigned short* __restrict__ qws, const unsigned short* __restrict__ kws,
    const unsigned short* __restrict__ vtws, unsigned short* __restrict__ ctx)
{
    __shared__ __align__(16) unsigned short Qs[128 * 64];  // swizzled rows
    __shared__ __align__(16) unsigned short Ks[64 * 64];   // swizzled rows
    __shared__ __align__(16) unsigned short Vt[64][72];    // padded [d][key]

    const int tid = threadIdx.x;
    const int wave = tid >> 6, lane = tid & 63, quad = lane >> 4, l16 = lane & 15;
    const int lrow = lane >> 3, lgrp = lane & 7;
    const int sg = lgrp ^ lrow;

    // work mapping: long tiles first; blocks i and i+256 pair tiles t and 15-t
    const int i = blockIdx.x;
    const int idx = i & 255;
    const int tile = (i < 256) ? (15 - (idx >> 5)) : (idx >> 5);
    const int bh = idx & 31;
    const int q0 = tile * 128;

    const unsigned short* Q  = qws + (size_t)bh * 2048 * 64;
    const unsigned short* Kp = kws + (size_t)bh * 2048 * 64;
    const unsigned short* Vp = vtws + (size_t)bh * 64 * 2048;

#pragma unroll
    for (int c = 0; c < 4; c++) {
        int rb = (wave * 4 + c) * 8;
        async_copy16(Q + (size_t)(q0 + rb + lrow) * 64 + sg * 8, &Qs[rb * 64]);
    }

    const int wq = wave * 32;
    f32x4 o[4][2];  // [d-tile][q-tile], O^T C-layout: d=quad*4+r, q=l16
    const f32x4 Z4 = {0.f, 0.f, 0.f, 0.f};
#pragma unroll
    for (int dt = 0; dt < 4; dt++)
#pragma unroll
        for (int qt = 0; qt < 2; qt++) o[dt][qt] = Z4;
    float lsum[2] = {0.f, 0.f};

    const int jmax = tile * 2 + 2;
    for (int j = 0; j < jmax; j++) {
        const int kb0 = j * 64;
        __syncthreads();
#pragma unroll
        for (int c = 0; c < 2; c++) {
            int rb = (wave * 2 + c) * 8;
            async_copy16(Kp + (size_t)(kb0 + rb + lrow) * 64 + sg * 8, &Ks[rb * 64]);
        }
#pragma unroll
        for (int ii = 0; ii < 2; ii++) {
            int id2 = tid + ii * 256;
            int row = id2 >> 3, c = (id2 & 7) * 8;
            *(uint4*)&Vt[row][c] = *(const uint4*)(Vp + (size_t)row * 2048 + kb0 + c);
        }
        __syncthreads();

        if (kb0 <= q0 + wq + 31) {  // wave-uniform: skip fully-masked quadrants
            f32x4 sc[4][2];
#pragma unroll
            for (int kt = 0; kt < 4; kt++)
#pragma unroll
                for (int qt = 0; qt < 2; qt++) sc[kt][qt] = Z4;
#pragma unroll
            for (int kk = 0; kk < 2; kk++) {
                int pg = ((kk * 4 + quad) ^ (l16 & 7)) * 8;
                bf16x8 ak[4], bq[2];
#pragma unroll
                for (int kt = 0; kt < 4; kt++) ak[kt] = *(const bf16x8*)&Ks[(kt * 16 + l16) * 64 + pg];
#pragma unroll
                for (int qt = 0; qt < 2; qt++) bq[qt] = *(const bf16x8*)&Qs[(wq + qt * 16 + l16) * 64 + pg];
#pragma unroll
                for (int kt = 0; kt < 4; kt++)
#pragma unroll
                    for (int qt = 0; qt < 2; qt++)
                        sc[kt][qt] = __builtin_amdgcn_mfma_f32_16x16x32_bf16(ak[kt], bq[qt], sc[kt][qt], 0, 0, 0);
            }
            short4v pb[4][2];
#pragma unroll
            for (int qt = 0; qt < 2; qt++) {
                int qg = q0 + wq + qt * 16 + l16;
#pragma unroll
                for (int kt = 0; kt < 4; kt++) {
#pragma unroll
                    for (int r = 0; r < 4; r++) {
                        int key = kb0 + kt * 16 + quad * 4 + r;
                        float p = exp2f(sc[kt][qt][r]);
                        p = (key <= qg) ? p : 0.f;
                        lsum[qt] += p;
                        pb[kt][qt][r] = (short)f2bf(p);
                    }
                }
            }
#pragma unroll
            for (int kt = 0; kt < 4; kt++) {
#pragma unroll
                for (int dt = 0; dt < 4; dt++) {
                    short4v av = *(const short4v*)&Vt[dt * 16 + l16][kt * 16 + quad * 4];
#pragma unroll
                    for (int qt = 0; qt < 2; qt++)
                        o[dt][qt] = mfma16x16x16(av, pb[kt][qt], o[dt][qt]);
                }
            }
        }
    }
#pragma unroll
    for (int qt = 0; qt < 2; qt++) {
        lsum[qt] += __shfl_xor(lsum[qt], 16);
        lsum[qt] += __shfl_xor(lsum[qt], 32);
    }
    const int b = bh >> 4, h = bh & 15;
#pragma unroll
    for (int qt = 0; qt < 2; qt++) {
        int qg = q0 + wq + qt * 16 + l16;
        float inv = 1.0f / lsum[qt];
#pragma unroll
        for (int dt = 0; dt < 4; dt++) {
            ushort4 ov;
            ov.x = f2bf(o[dt][qt][0] * inv);
            ov.y = f2bf(o[dt][qt][1] * inv);
            ov.z = f2bf(o[dt][qt][2] * inv);
            ov.w = f2bf(o[dt][qt][3] * inv);
            *(ushort4*)(ctx + (size_t)(b * 2048 + qg) * 1024 + h * 64 + dt * 16 + quad * 4) = ov;
        }
    }
}

// ---------------- GEMM2: out = ctx @ Wo + bo (fp32 out) ----------------
__global__ __launch_bounds__(256) void gemm_out(
    const unsigned short* __restrict__ Ctx, const unsigned short* __restrict__ WT,
    const float* __restrict__ bias, float* __restrict__ Out)
{
    const int K = 1024, N = 1024;
    __shared__ __align__(16) unsigned short As[128 * 64];
    __shared__ __align__(16) unsigned short Bs[128 * 64];
    const int tid = threadIdx.x;
    const int m0 = blockIdx.y * 128, n0 = blockIdx.x * 128;
    const int wave = tid >> 6, lane = tid & 63;
    const int wm = (wave >> 1) * 64, wn = (wave & 1) * 64;
    const int quad = lane >> 4, l16 = lane & 15;
    const int lrow = lane >> 3, lgrp = lane & 7;
    const int sg = lgrp ^ lrow;

    f32x4 acc[4][4];
    const f32x4 Z4 = {0.f, 0.f, 0.f, 0.f};
#pragma unroll
    for (int i = 0; i < 4; i++)
#pragma unroll
        for (int j = 0; j < 4; j++) acc[i][j] = Z4;

    for (int k0 = 0; k0 < K; k0 += 64) {
        __syncthreads();
#pragma unroll
        for (int c = 0; c < 4; c++) {
            int nb = (wave * 4 + c) * 8;
            async_copy16(Ctx + (size_t)(m0 + nb + lrow) * K + k0 + sg * 8, &As[nb * 64]);
            async_copy16(WT  + (size_t)(n0 + nb + lrow) * K + k0 + sg * 8, &Bs[nb * 64]);
        }
        __syncthreads();
#pragma unroll
        for (int kk = 0; kk < 2; kk++) {
            int pg = ((kk * 4 + quad) ^ (l16 & 7)) * 8;
            bf16x8 af[4], bfr[4];
#pragma unroll
            for (int mi = 0; mi < 4; mi++) af[mi] = *(const bf16x8*)&As[(wm + mi * 16 + l16) * 64 + pg];
#pragma unroll
            for (int ni = 0; ni < 4; ni++) bfr[ni] = *(const bf16x8*)&Bs[(wn + ni * 16 + l16) * 64 + pg];
#pragma unroll
            for (int mi = 0; mi < 4; mi++)
#pragma unroll
                for (int ni = 0; ni < 4; ni++)
                    acc[mi][ni] = __builtin_amdgcn_mfma_f32_16x16x32_bf16(af[mi], bfr[ni], acc[mi][ni], 0, 0, 0);
        }
    }
#pragma unroll
    for (int mi = 0; mi < 4; mi++)
#pragma unroll
        for (int ni = 0; ni < 4; ni++) {
            int col = n0 + wn + ni * 16 + l16;
            float bv = bias[col];
#pragma unroll
            for (int r = 0; r < 4; r++) {
                int row = m0 + wm + mi * 16 + quad * 4 + r;
                Out[(size_t)row * N + col] = acc[mi][ni][r] + bv;
            }
        }
}

extern "C" void kernel_launch(void* const* d_in, const int* in_sizes, int n_in,
                              void* d_out, int out_size, void* d_ws, size_t ws_size,
                              hipStream_t stream) {
    const float* x    = (const float*)d_in[0];
    const float* Wqkv = (const float*)d_in[1];
    const float* bqkv = (const float*)d_in[2];
    const float* Wo   = (const float*)d_in[3];
    const float* bo   = (const float*)d_in[4];
    float* out = (float*)d_out;

    const size_t R = 4194304;  // ushorts per region (8 MB)
    unsigned short* q   = (unsigned short*)d_ws;
    unsigned short* k   = q + R;
    unsigned short* vt  = k + R;
    unsigned short* ctx = vt + R;
    unsigned short* xbf = ctx + R;               // optional 5th region
    unsigned short* wqkvT = ctx;                 // alias: dead until attn runs
    unsigned short* woT   = q;                   // alias: q dead after attn

    transpose_f32_bf16<<<dim3(48, 16), 256, 0, stream>>>(Wqkv, wqkvT, 1024, 3072);
    if (ws_size >= 5 * R * sizeof(unsigned short)) {
        convert_f32_bf16<<<dim3(2048), 256, 0, stream>>>(x, xbf);
        gemm_qkv_bf<<<dim3(24, 32), 256, 0, stream>>>(xbf, wqkvT, bqkv, q, k, vt);
    } else {
        gemm_qkv<<<dim3(24, 32), 256, 0, stream>>>(x, wqkvT, bqkv, q, k, vt);
    }
    attn<<<dim3(512), 256, 0, stream>>>(q, k, vt, ctx);
    transpose_f32_bf16<<<dim3(16, 16), 256, 0, stream>>>(Wo, woT, 1024, 1024);
    gemm_out<<<dim3(8, 32), 256, 0, stream>>>(ctx, woT, bo, out);
}